// Round 1
// baseline (469.053 us; speedup 1.0000x reference)
//
#include <hip/hip_runtime.h>
#include <hip/hip_cooperative_groups.h>

namespace cg = cooperative_groups;

static constexpr int D = 2048;
static constexpr int H = 4096;
static constexpr int KSTEP = 4;
static constexpr int MAX_STEPS = 64;
static constexpr float MOMC = 0.9f;
static constexpr float THRC = 0.01f;

static constexpr int GRID = 256;
static constexpr int BLOCK = 512;

struct Params {
  const float* query;
  const float* hg_Wih; const float* hg_Whh; const float* hg_bih; const float* hg_bhh;
  const float* hd_W; const float* hd_b;
  const float* hc_W; const float* hc_b;
  const float* lg_Wih; const float* lg_Whh; const float* lg_bih; const float* lg_bhh;
  const float* lo_W; const float* lo_b;
  const float* halt_W; const float* halt_b;
  const float* reset_W; const float* reset_b;
  const float* li_W; const float* li_b;
  float* ws; float* out;
};

__device__ __forceinline__ float sigmoidf_(float x) { return 1.f / (1.f + expf(-x)); }

// Accumulate partial dot over this wave's lanes (no reduce). len % 256 == 0.
__device__ __forceinline__ float dotp(const float* __restrict__ row,
                                      const float* __restrict__ vec,
                                      int len, int lane, float acc) {
  for (int k = lane * 4; k < len; k += 256) {
    float4 a = *reinterpret_cast<const float4*>(row + k);
    float4 b = *reinterpret_cast<const float4*>(vec + k);
    acc = fmaf(a.x, b.x, acc);
    acc = fmaf(a.y, b.y, acc);
    acc = fmaf(a.z, b.z, acc);
    acc = fmaf(a.w, b.w, acc);
  }
  return acc;
}

__device__ __forceinline__ float wred(float v) {
  #pragma unroll
  for (int off = 1; off < 64; off <<= 1) v += __shfl_xor(v, off, 64);
  return v;
}

__global__ void __launch_bounds__(BLOCK) reasoning_kernel(Params p) {
  cg::grid_group grid = cg::this_grid();
  const int tid = blockIdx.x * blockDim.x + threadIdx.x;
  const int nth = gridDim.x * blockDim.x;
  const int lane = threadIdx.x & 63;
  const int gw = tid >> 6;
  const int nw = nth >> 6;

  // workspace layout (floats)
  float* hb[2]; hb[0] = p.ws; hb[1] = p.ws + H;
  float* lb[2]; lb[0] = p.ws + 2 * H; lb[1] = p.ws + 2 * H + D;
  float* dirv  = p.ws + 2 * H + 2 * D;   // D
  float* ghl   = dirv + D;               // 3D
  float* resv  = ghl + 3 * D;            // D
  float* sumv  = resv + D;               // D (result accumulator)
  float* lastv = sumv + D;               // D
  float* scal  = lastv + D;              // 8 scalars: 0=rawconv 1=halt_h 2=reset_h 3=halt_l 4=reset_l

  // init persistent state (ws is poisoned 0xAA before timing)
  for (int i = tid; i < H; i += nth) hb[0][i] = 0.f;
  for (int i = tid; i < D; i += nth) { lb[0][i] = 0.f; sumv[i] = 0.f; lastv[i] = 0.f; }
  grid.sync();

  // scalar state, replicated (identical) on every thread
  float cum = 0.f, rw = 0.f, mom = 0.f, best = 0.f;
  int ph = 0, pl = 0;

  for (int step = 0; step < MAX_STEPS; ++step) {
    // every executed step has active == true (we break once converged,
    // and after convergence the reference state is frozen)
    const float* l = lb[pl];

    // ---- Phase A: h-GRU (every K-th step) ----
    if ((step % KSTEP) == 0) {
      const float* h = hb[ph];
      float* hn = hb[ph ^ 1];
      for (int i = gw; i < H; i += nw) {
        const float* w0 = p.hg_Wih + (size_t)i * (2 * D);
        const float* w1 = p.hg_Wih + (size_t)(H + i) * (2 * D);
        const float* w2 = p.hg_Wih + (size_t)(2 * H + i) * (2 * D);
        const float* u0 = p.hg_Whh + (size_t)i * H;
        const float* u1 = p.hg_Whh + (size_t)(H + i) * H;
        const float* u2 = p.hg_Whh + (size_t)(2 * H + i) * H;
        float a0 = dotp(w0, p.query, D, lane, 0.f); a0 = dotp(w0 + D, l, D, lane, a0);
        float a1 = dotp(w1, p.query, D, lane, 0.f); a1 = dotp(w1 + D, l, D, lane, a1);
        float a2 = dotp(w2, p.query, D, lane, 0.f); a2 = dotp(w2 + D, l, D, lane, a2);
        float b0 = dotp(u0, h, H, lane, 0.f);
        float b1 = dotp(u1, h, H, lane, 0.f);
        float b2 = dotp(u2, h, H, lane, 0.f);
        float gir = wred(a0) + p.hg_bih[i];
        float giz = wred(a1) + p.hg_bih[H + i];
        float gin = wred(a2) + p.hg_bih[2 * H + i];
        float ghr = wred(b0) + p.hg_bhh[i];
        float ghz = wred(b1) + p.hg_bhh[H + i];
        float ghn = wred(b2) + p.hg_bhh[2 * H + i];
        if (lane == 0) {
          float r = sigmoidf_(gir + ghr);
          float z = sigmoidf_(giz + ghz);
          float n = tanhf(gin + r * ghn);
          hn[i] = (1.f - z) * n + z * h[i];
        }
      }
      ph ^= 1;
      grid.sync();
    }
    const float* h = hb[ph];

    // ---- Phase B: directive = tanh(hd_W @ h + b); ghl = lg_Whh @ l + b;
    //               rawconv, halt_h-part, reset_h-part ----
    for (int t = gw; t < 4 * D + 3; t += nw) {
      if (t < D) {
        float a = dotp(p.hd_W + (size_t)t * H, h, H, lane, 0.f);
        float v = wred(a) + p.hd_b[t];
        if (lane == 0) dirv[t] = tanhf(v);
      } else if (t < 4 * D) {
        int j = t - D;
        float a = dotp(p.lg_Whh + (size_t)j * D, l, D, lane, 0.f);
        float v = wred(a) + p.lg_bhh[j];
        if (lane == 0) ghl[j] = v;
      } else if (t == 4 * D) {
        float a = dotp(p.hc_W, h, H, lane, 0.f);
        float v = wred(a) + p.hc_b[0];
        if (lane == 0) scal[0] = sigmoidf_(v);
      } else if (t == 4 * D + 1) {
        float a = dotp(p.halt_W, h, H, lane, 0.f);
        float v = wred(a);
        if (lane == 0) scal[1] = v;
      } else {
        float a = dotp(p.reset_W, h, H, lane, 0.f);
        float v = wred(a);
        if (lane == 0) scal[2] = v;
      }
    }
    grid.sync();

    // momentum update (uniform on all threads)
    mom = MOMC * mom + (1.f - MOMC) * scal[0];
    const float conv = mom;

    // ---- Phase C: l-GRU combine (lg_Wih @ directive, stashed ghl) ----
    {
      float* lnew = lb[pl ^ 1];
      for (int j = gw; j < D; j += nw) {
        float a0 = dotp(p.lg_Wih + (size_t)j * D, dirv, D, lane, 0.f);
        float a1 = dotp(p.lg_Wih + (size_t)(D + j) * D, dirv, D, lane, 0.f);
        float a2 = dotp(p.lg_Wih + (size_t)(2 * D + j) * D, dirv, D, lane, 0.f);
        float gir = wred(a0) + p.lg_bih[j];
        float giz = wred(a1) + p.lg_bih[D + j];
        float gin = wred(a2) + p.lg_bih[2 * D + j];
        if (lane == 0) {
          float r = sigmoidf_(gir + ghl[j]);
          float z = sigmoidf_(giz + ghl[D + j]);
          float n = tanhf(gin + r * ghl[2 * D + j]);
          lnew[j] = (1.f - z) * n + z * l[j];
        }
      }
      pl ^= 1;
      grid.sync();
    }
    const float* l2 = lb[pl];

    // ---- Phase D: res = tanh(lo_W @ l2 + b); halt_l-part; reset_l-part ----
    for (int t = gw; t < D + 2; t += nw) {
      if (t < D) {
        float a = dotp(p.lo_W + (size_t)t * D, l2, D, lane, 0.f);
        float v = wred(a) + p.lo_b[t];
        if (lane == 0) resv[t] = tanhf(v);
      } else if (t == D) {
        float a = dotp(p.halt_W + H, l2, D, lane, 0.f);
        float v = wred(a);
        if (lane == 0) scal[3] = v;
      } else {
        float a = dotp(p.reset_W + H, l2, D, lane, 0.f);
        float v = wred(a);
        if (lane == 0) scal[4] = v;
      }
    }
    grid.sync();

    // ---- Phase E: scalar updates (uniform), result accumulate, optional reset ----
    float halt = sigmoidf_(scal[1] + scal[3] + p.halt_b[0]);
    float pp = fminf(halt, 1.f - cum);
    float cum_new = cum + pp;
    bool converged = cum_new > 0.95f;
    float reset_p = sigmoidf_(scal[2] + scal[4] + p.reset_W[H + D] * conv + p.reset_b[0]);
    bool do_reset = (!converged) && (reset_p > 0.7f) && (step > KSTEP);
    if (conv > best + THRC) best = conv;
    cum = cum_new;
    rw += pp;

    for (int j = tid; j < D; j += nth) {
      float r = resv[j];
      sumv[j] = sumv[j] + pp * r;
      lastv[j] = r;
    }
    if (do_reset) {
      float* lcur = lb[pl];
      for (int j = gw; j < D; j += nw) {
        float a = dotp(p.li_W + (size_t)j * H, h, H, lane, 0.f);
        float v = wred(a) + p.li_b[j];
        if (lane == 0) lcur[j] = tanhf(v);
      }
    }
    grid.sync();

    if (converged) break;
  }

  // ---- Output ----
  for (int j = tid; j < D; j += nth) {
    p.out[j] = (rw > 0.f) ? (sumv[j] / fmaxf(rw, 1e-8f)) : lastv[j];
  }
}

extern "C" void kernel_launch(void* const* d_in, const int* in_sizes, int n_in,
                              void* d_out, int out_size, void* d_ws, size_t ws_size,
                              hipStream_t stream) {
  Params prm;
  prm.query   = (const float*)d_in[0];
  prm.hg_Wih  = (const float*)d_in[1];
  prm.hg_Whh  = (const float*)d_in[2];
  prm.hg_bih  = (const float*)d_in[3];
  prm.hg_bhh  = (const float*)d_in[4];
  prm.hd_W    = (const float*)d_in[5];
  prm.hd_b    = (const float*)d_in[6];
  prm.hc_W    = (const float*)d_in[7];
  prm.hc_b    = (const float*)d_in[8];
  prm.lg_Wih  = (const float*)d_in[9];
  prm.lg_Whh  = (const float*)d_in[10];
  prm.lg_bih  = (const float*)d_in[11];
  prm.lg_bhh  = (const float*)d_in[12];
  prm.lo_W    = (const float*)d_in[13];
  prm.lo_b    = (const float*)d_in[14];
  prm.halt_W  = (const float*)d_in[15];
  prm.halt_b  = (const float*)d_in[16];
  prm.reset_W = (const float*)d_in[17];
  prm.reset_b = (const float*)d_in[18];
  prm.li_W    = (const float*)d_in[19];
  prm.li_b    = (const float*)d_in[20];
  prm.ws  = (float*)d_ws;
  prm.out = (float*)d_out;

  void* args[] = { &prm };
  hipLaunchCooperativeKernel((const void*)reasoning_kernel,
                             dim3(GRID), dim3(BLOCK), args, 0, stream);
}

// Round 3
// 278.616 us; speedup vs baseline: 1.6835x; 1.6835x over previous
//
#include <hip/hip_runtime.h>
#include <hip/hip_cooperative_groups.h>

namespace cg = cooperative_groups;

static constexpr int D = 2048;
static constexpr int H = 4096;
static constexpr int KSTEP = 4;
static constexpr int MAX_STEPS = 64;
static constexpr float MOMC = 0.9f;

static constexpr int GRID = 256;
static constexpr int BLOCK = 1024;

struct Params {
  const float* query;
  const float* hg_Wih; const float* hg_Whh; const float* hg_bih; const float* hg_bhh;
  const float* hd_W; const float* hd_b;
  const float* hc_W; const float* hc_b;
  const float* lg_Wih; const float* lg_Whh; const float* lg_bih; const float* lg_bhh;
  const float* lo_W; const float* lo_b;
  const float* halt_W; const float* halt_b;
  const float* reset_W; const float* reset_b;
  const float* li_W; const float* li_b;
  float* ws; float* out;
};

__device__ __forceinline__ float sigmoidf_(float x) { return 1.f / (1.f + expf(-x)); }

// Per-lane partial dot, 4 independent accumulators / 4 load streams.
// LEN is a multiple of 1024 (2048 or 4096). row: global; vec: LDS or global.
template<int LEN>
__device__ __forceinline__ float dotw(const float* __restrict__ row,
                                      const float* __restrict__ vec, int lane) {
  float s0 = 0.f, s1 = 0.f, s2 = 0.f, s3 = 0.f;
  #pragma unroll
  for (int k = 0; k < LEN; k += 1024) {
    int i = k + lane * 4;
    float4 a0 = *reinterpret_cast<const float4*>(row + i);
    float4 a1 = *reinterpret_cast<const float4*>(row + i + 256);
    float4 a2 = *reinterpret_cast<const float4*>(row + i + 512);
    float4 a3 = *reinterpret_cast<const float4*>(row + i + 768);
    float4 b0 = *reinterpret_cast<const float4*>(vec + i);
    float4 b1 = *reinterpret_cast<const float4*>(vec + i + 256);
    float4 b2 = *reinterpret_cast<const float4*>(vec + i + 512);
    float4 b3 = *reinterpret_cast<const float4*>(vec + i + 768);
    s0 = fmaf(a0.x, b0.x, s0); s0 = fmaf(a0.y, b0.y, s0);
    s0 = fmaf(a0.z, b0.z, s0); s0 = fmaf(a0.w, b0.w, s0);
    s1 = fmaf(a1.x, b1.x, s1); s1 = fmaf(a1.y, b1.y, s1);
    s1 = fmaf(a1.z, b1.z, s1); s1 = fmaf(a1.w, b1.w, s1);
    s2 = fmaf(a2.x, b2.x, s2); s2 = fmaf(a2.y, b2.y, s2);
    s2 = fmaf(a2.z, b2.z, s2); s2 = fmaf(a2.w, b2.w, s2);
    s3 = fmaf(a3.x, b3.x, s3); s3 = fmaf(a3.y, b3.y, s3);
    s3 = fmaf(a3.z, b3.z, s3); s3 = fmaf(a3.w, b3.w, s3);
  }
  return (s0 + s1) + (s2 + s3);
}

__device__ __forceinline__ float wred(float v) {
  #pragma unroll
  for (int off = 1; off < 64; off <<= 1) v += __shfl_xor(v, off, 64);
  return v;
}

__global__ void __launch_bounds__(BLOCK, 4) reasoning_kernel(Params p) {
  cg::grid_group grid = cg::this_grid();
  const int tid = blockIdx.x * blockDim.x + threadIdx.x;
  const int nth = gridDim.x * blockDim.x;
  const int lane = threadIdx.x & 63;
  const int gw = tid >> 6;
  const int nw = nth >> 6;

  __shared__ __align__(16) float sh_h[H];   // block-local current h (identical across blocks)
  __shared__ __align__(16) float sh_l[D];   // block-local current l (identical across blocks)

  // workspace layout (floats)
  float* qc    = p.ws;             // 3H  hg_Wih[:, :D] @ q  (step-invariant)
  float* gi    = qc + 3 * H;       // 3H  hg_Wih @ [q;l] + bih
  float* gh    = gi + 3 * H;       // 3H  hg_Whh @ h + bhh
  float* ghl   = gh + 3 * H;       // 3D  lg_Whh @ l + bhh
  float* gil   = ghl + 3 * D;      // 3D  lg_Wih @ dirv + bih (cached between h-updates)
  float* dirv  = gil + 3 * D;      // D
  float* resv  = dirv + D;         // D
  float* sumv  = resv + D;         // D
  float* lastv = sumv + D;         // D
  float* lreset= lastv + D;        // D  (only written on reset steps)
  float* scal  = lreset + D;       // 8: 0=rawconv 1=halt_h 2=reset_h 3=halt_l 4=reset_l

  // init: h = l = 0 so gh and ghl start as pure biases; sumv/lastv zero
  for (int i = tid; i < 3 * H; i += nth) gh[i] = p.hg_bhh[i];
  for (int i = tid; i < 3 * D; i += nth) ghl[i] = p.lg_bhh[i];
  for (int i = tid; i < D; i += nth) { sumv[i] = 0.f; lastv[i] = 0.f; }
  for (int i = threadIdx.x; i < H; i += blockDim.x) sh_h[i] = 0.f;
  for (int i = threadIdx.x; i < D; i += blockDim.x) sh_l[i] = 0.f;
  grid.sync();

  float cum = 0.f, rw = 0.f, mom = 0.f;
  bool prev_reset = false;

  for (int step = 0; step < MAX_STEPS; ++step) {
    const bool upd = (step % KSTEP) == 0;

    if (prev_reset) {  // uniform: reload l replaced by the reset projection
      for (int j = threadIdx.x; j < D; j += blockDim.x) sh_l[j] = lreset[j];
      __syncthreads();
      prev_reset = false;
    }

    if (upd) {
      // ---- P1: independent dots on (h_old, l_old) ----
      if (step == 0) {
        // h = l = 0: gh/ghl already hold biases; only the q-part of gi is nonzero
        for (int t = gw; t < 3 * H; t += nw) {
          float s = dotw<D>(p.hg_Wih + (size_t)t * (2 * D), p.query, lane);
          float v = wred(s);
          if (lane == 0) { qc[t] = v; gi[t] = v + p.hg_bih[t]; }
        }
      } else {
        const int T1 = 6 * H + 3 * D;
        for (int t = gw; t < T1; t += nw) {
          if (t < 3 * H) {
            float s = dotw<D>(p.hg_Wih + (size_t)t * (2 * D) + D, sh_l, lane);
            float v = wred(s);
            if (lane == 0) gi[t] = v + qc[t] + p.hg_bih[t];
          } else if (t < 6 * H) {
            int k = t - 3 * H;
            float s = dotw<H>(p.hg_Whh + (size_t)k * H, sh_h, lane);
            float v = wred(s) + p.hg_bhh[k];
            if (lane == 0) gh[k] = v;
          } else {
            int j = t - 6 * H;
            float s = dotw<D>(p.lg_Whh + (size_t)j * D, sh_l, lane);
            float v = wred(s) + p.lg_bhh[j];
            if (lane == 0) ghl[j] = v;
          }
        }
      }
      grid.sync();

      // ---- P2: h-GRU combine, block-locally into LDS (identical everywhere) ----
      for (int i = threadIdx.x; i < H; i += blockDim.x) {
        float r = sigmoidf_(gi[i] + gh[i]);
        float z = sigmoidf_(gi[H + i] + gh[H + i]);
        float n = tanhf(gi[2 * H + i] + r * gh[2 * H + i]);
        sh_h[i] = (1.f - z) * n + z * sh_h[i];
      }
      __syncthreads();

      // ---- P3: h-derived dots: directive, rawconv, halt_h, reset_h ----
      for (int t = gw; t < D + 3; t += nw) {
        if (t < D) {
          float s = dotw<H>(p.hd_W + (size_t)t * H, sh_h, lane);
          float v = wred(s) + p.hd_b[t];
          if (lane == 0) dirv[t] = tanhf(v);
        } else if (t == D) {
          float s = dotw<H>(p.hc_W, sh_h, lane);
          float v = wred(s) + p.hc_b[0];
          if (lane == 0) scal[0] = sigmoidf_(v);
        } else if (t == D + 1) {
          float s = dotw<H>(p.halt_W, sh_h, lane);
          float v = wred(s);
          if (lane == 0) scal[1] = v;
        } else {
          float s = dotw<H>(p.reset_W, sh_h, lane);
          float v = wred(s);
          if (lane == 0) scal[2] = v;
        }
      }
      grid.sync();

      // ---- P4: gil = lg_Wih @ dirv + bih (cached until next h-update) ----
      for (int j = gw; j < 3 * D; j += nw) {
        float s = dotw<D>(p.lg_Wih + (size_t)j * D, dirv, lane);
        float v = wred(s) + p.lg_bih[j];
        if (lane == 0) gil[j] = v;
      }
      grid.sync();
    } else {
      // ---- P1': only ghl depends on l; all h-derived values are cached ----
      for (int j = gw; j < 3 * D; j += nw) {
        float s = dotw<D>(p.lg_Whh + (size_t)j * D, sh_l, lane);
        float v = wred(s) + p.lg_bhh[j];
        if (lane == 0) ghl[j] = v;
      }
      grid.sync();
    }

    // momentum update (uniform; scal[0] cached on non-update steps)
    mom = MOMC * mom + (1.f - MOMC) * scal[0];
    const float conv = mom;

    // ---- P5: l-GRU combine, block-locally into LDS ----
    for (int j = threadIdx.x; j < D; j += blockDim.x) {
      float r = sigmoidf_(gil[j] + ghl[j]);
      float z = sigmoidf_(gil[D + j] + ghl[D + j]);
      float n = tanhf(gil[2 * D + j] + r * ghl[2 * D + j]);
      sh_l[j] = (1.f - z) * n + z * sh_l[j];
    }
    __syncthreads();

    // ---- P6: l-derived dots: res, halt_l, reset_l ----
    for (int t = gw; t < D + 2; t += nw) {
      if (t < D) {
        float s = dotw<D>(p.lo_W + (size_t)t * D, sh_l, lane);
        float v = wred(s) + p.lo_b[t];
        if (lane == 0) resv[t] = tanhf(v);
      } else if (t == D) {
        float s = dotw<D>(p.halt_W + H, sh_l, lane);
        float v = wred(s);
        if (lane == 0) scal[3] = v;
      } else {
        float s = dotw<D>(p.reset_W + H, sh_l, lane);
        float v = wred(s);
        if (lane == 0) scal[4] = v;
      }
    }
    grid.sync();

    // ---- P7: uniform scalar update, accumulate, optional reset ----
    float halt = sigmoidf_(scal[1] + scal[3] + p.halt_b[0]);
    float pp = fminf(halt, 1.f - cum);
    float cumn = cum + pp;
    bool converged = cumn > 0.95f;
    float reset_p = sigmoidf_(scal[2] + scal[4] + p.reset_W[H + D] * conv + p.reset_b[0]);
    bool do_reset = (!converged) && (reset_p > 0.7f) && (step > KSTEP);
    cum = cumn; rw += pp;

    for (int j = tid; j < D; j += nth) {
      float r = resv[j];
      sumv[j] += pp * r;
      lastv[j] = r;
    }
    if (do_reset) {
      for (int j = gw; j < D; j += nw) {
        float s = dotw<H>(p.li_W + (size_t)j * H, sh_h, lane);
        float v = wred(s) + p.li_b[j];
        if (lane == 0) lreset[j] = tanhf(v);
      }
      grid.sync();  // uniform branch: all blocks take it together
      prev_reset = true;
    }

    if (converged) break;
  }

  for (int j = tid; j < D; j += nth) {
    p.out[j] = (rw > 0.f) ? (sumv[j] / fmaxf(rw, 1e-8f)) : lastv[j];
  }
}

extern "C" void kernel_launch(void* const* d_in, const int* in_sizes, int n_in,
                              void* d_out, int out_size, void* d_ws, size_t ws_size,
                              hipStream_t stream) {
  Params prm;
  prm.query   = (const float*)d_in[0];
  prm.hg_Wih  = (const float*)d_in[1];
  prm.hg_Whh  = (const float*)d_in[2];
  prm.hg_bih  = (const float*)d_in[3];
  prm.hg_bhh  = (const float*)d_in[4];
  prm.hd_W    = (const float*)d_in[5];
  prm.hd_b    = (const float*)d_in[6];
  prm.hc_W    = (const float*)d_in[7];
  prm.hc_b    = (const float*)d_in[8];
  prm.lg_Wih  = (const float*)d_in[9];
  prm.lg_Whh  = (const float*)d_in[10];
  prm.lg_bih  = (const float*)d_in[11];
  prm.lg_bhh  = (const float*)d_in[12];
  prm.lo_W    = (const float*)d_in[13];
  prm.lo_b    = (const float*)d_in[14];
  prm.halt_W  = (const float*)d_in[15];
  prm.halt_b  = (const float*)d_in[16];
  prm.reset_W = (const float*)d_in[17];
  prm.reset_b = (const float*)d_in[18];
  prm.li_W    = (const float*)d_in[19];
  prm.li_b    = (const float*)d_in[20];
  prm.ws  = (float*)d_ws;
  prm.out = (float*)d_out;

  void* args[] = { &prm };
  // 256 blocks (1/CU) is a proven-launchable cooperative config; fall back to
  // smaller grids if the runtime ever rejects co-residency. All device loops
  // are grid-stride, so correctness is grid-size independent.
  const int grids[3] = { GRID, GRID / 2, GRID / 4 };
  for (int g = 0; g < 3; ++g) {
    hipError_t e = hipLaunchCooperativeKernel((const void*)reasoning_kernel,
                                              dim3(grids[g]), dim3(BLOCK),
                                              args, 0, stream);
    if (e == hipSuccess) break;
  }
}